// Round 4
// baseline (426.512 us; speedup 1.0000x reference)
//
#include <hip/hip_runtime.h>
#include <math.h>

typedef __attribute__((ext_vector_type(4))) float f32x4;
typedef __attribute__((ext_vector_type(2))) float f32x2;
typedef __attribute__((ext_vector_type(4))) short s16x4;

#define LOG2E   1.4426950408889634f
#define EPSV    2.220446049250313e-16f
#define HLOG2PI 0.9189385332046727f

// Schraudolph-to-bf16: U = e128 + MAGIC (f32 add rounds to ulp=1 since
// U in [2^23,2^24)); low16(bits(U)) == bf16 bits of ~2^(e128/128).
// MAGIC = 1.5*2^23 + 127*128 + (128*sigma - 0.5), sigma = -0.0573.
// MAGIC is folded into the 'a' coefficient at prep time.
#define MAGICC  12599160.0f

static __device__ __forceinline__ float fexp2(float x) {
  return __builtin_amdgcn_exp2f(x);
}

// [hi16(f1)]:[hi16(f0)] -> bf16 trunc pack, one v_perm_b32
static __device__ __forceinline__ unsigned pk_bf16t(float f0, float f1) {
  return __builtin_amdgcn_perm(__builtin_bit_cast(unsigned, f1),
                               __builtin_bit_cast(unsigned, f0), 0x07060302u);
}
// [lo16(u1)]:[lo16(u0)] -> Schraudolph bf16 bits, one v_perm_b32
static __device__ __forceinline__ unsigned pk_lo16(f32x2 u) {
  return __builtin_amdgcn_perm(__builtin_bit_cast(uint2, u).y,
                               __builtin_bit_cast(uint2, u).x, 0x05040100u);
}

static __device__ __forceinline__ float rdlane(float v, int lane) {
  return __builtin_bit_cast(float,
      __builtin_amdgcn_readlane(__builtin_bit_cast(int, v), lane));
}

// ---------------------------------------------------------------------------
// Prep: fold log_softmax(W_logits, axis=1), softplus(pre_sigma), mu into
// per-entry quadratic coefficients scaled by 128*log2(e), with the
// Schraudolph magic constant folded into 'a':
//   U[m,k,j](x) = a + b*x + c*x^2 ;  low16(bits(U)) = bf16(R entry)
// Layout: group g = m*64 + k*4 + q  (q = j/4) -> 3 consecutive float4 {a,b,c}.
// ---------------------------------------------------------------------------
__global__ void tt_prep(const float* __restrict__ Wl,
                        const float* __restrict__ mu,
                        const float* __restrict__ ps,
                        float* __restrict__ abc, int M) {
  int g = blockIdx.x * blockDim.x + threadIdx.x;
  if (g >= M * 64) return;
  int m = g >> 6;
  int k = (g >> 2) & 15;
  int q = g & 3;
  const float SC = 128.0f * LOG2E;
  float av[4], bv[4], cv[4];
#pragma unroll
  for (int i = 0; i < 4; ++i) {
    int j = q * 4 + i;
    int base = m * 256 + j;               // stride 16 over k'
    float mx = -INFINITY;
    for (int kk = 0; kk < 16; ++kk) mx = fmaxf(mx, Wl[base + kk * 16]);
    float s = 0.f;
    for (int kk = 0; kk < 16; ++kk) s += expf(Wl[base + kk * 16] - mx);
    float lse = mx + logf(s);
    int idx = m * 256 + k * 16 + j;
    float logw = Wl[idx] - lse;
    float p  = ps[idx];
    float sg = (p > 20.f) ? p : log1pf(expf(p));   // softplus
    float inv  = 1.0f / sg;
    float inv2 = inv * inv;
    float muv  = mu[idx];
    av[i] = SC * (logw - logf(sg) - HLOG2PI - 0.5f * muv * muv * inv2) + MAGICC;
    bv[i] = SC * (muv * inv2);
    cv[i] = SC * (-0.5f * inv2);
  }
  f32x4* o = (f32x4*)abc + (long)g * 3;
  o[0] = (f32x4){av[0], av[1], av[2], av[3]};
  o[1] = (f32x4){bv[0], bv[1], bv[2], bv[3]};
  o[2] = (f32x4){cv[0], cv[1], cv[2], cv[3]};
}

// ---------------------------------------------------------------------------
// Specialized main for M == 32. One wave = FOUR samples (was 8).
// Rationale: at 8 samples/wave the live set (~100 values) forced the
// allocator into a 44-VGPR + ~76-AGPR split; every phase-A v_perm read of
// an AGPR-homed D quad and every param access paid v_accvgpr_read —
// ~140 unmodeled VALU instrs/step (measured 510 cyc/step vs ~180 modeled).
// 4 samples/wave cuts the live set to ~70 values -> fits in arch VGPRs,
// copy tax gone. Per-sample VALU cost unchanged; wave count doubles.
// Two-phase step to break the MFMA->pack RAW hazard:
//   phase A: pack all 4 previous-step D quads (f32) into bf16 B-frags.
//   phase B: per sample: readlane x, quadratic via pk_fma, Schraudolph
//            lo16 pack + i16 clamp -> A-frag, issue MFMA.
// Params double-prefetched (2 steps ahead) to cover L2 latency.
// ---------------------------------------------------------------------------
__global__ __launch_bounds__(256, 4)
void tt_main32(const float* __restrict__ X,
               const float* __restrict__ wk0_logits,
               const float* __restrict__ abc,
               float* __restrict__ out, int N) {
  const int l = (int)(threadIdx.x & 63u);
  const int wave = __builtin_amdgcn_readfirstlane((int)(threadIdx.x >> 6));
  const int c = l & 15;   // A row / D col
  const int q = l >> 4;   // quad

  long nb = ((long)blockIdx.x * 4 + wave) * 4;
  if (nb > (long)N - 4) nb = (long)N - 4;   // tail clamp (duplicate work ok)

  // wk0 = softmax(wk0_logits); seed f32 state with wk0 (C/D-frag layout)
  float wl = wk0_logits[c];
  float mx = wl;
#pragma unroll
  for (int d = 1; d < 16; d <<= 1) mx = fmaxf(mx, __shfl_xor(mx, d, 64));
  float ew = fexp2((wl - mx) * LOG2E);
  float sw = ew;
#pragma unroll
  for (int d = 1; d < 16; d <<= 1) sw += __shfl_xor(sw, d, 64);
  float w0 = ew / sw;

  f32x4 q0;
#pragma unroll
  for (int i = 0; i < 4; ++i) q0[i] = __shfl(w0, 4 * q + i, 64);

  f32x4 Dv[4];
#pragma unroll
  for (int s = 0; s < 4; ++s) Dv[s] = q0;

  // one vector load: all 128 x values for this wave (2 per lane)
  // sample s, step m lives at lane s*16 + (m>>1), element m&1
  const float* Xn = X + nb * 32;
  f32x2 xq = *(const f32x2*)(Xn + l * 2);

  const int lofs = (c * 4 + q) * 12;        // per-lane float offset into a step
  // param pipeline: cur = step0, nxt = step1 (in flight), fut loaded per step
  f32x4 ca = *(const f32x4*)(abc + lofs);
  f32x4 cb = *(const f32x4*)(abc + lofs + 4);
  f32x4 cc = *(const f32x4*)(abc + lofs + 8);
  f32x4 na_ = *(const f32x4*)(abc + 768 + lofs);
  f32x4 nb_ = *(const f32x4*)(abc + 768 + lofs + 4);
  f32x4 nc_ = *(const f32x4*)(abc + 768 + lofs + 8);

  const f32x4 zero = (f32x4){0.f, 0.f, 0.f, 0.f};
  const s16x4 clmp = (s16x4){0x0080, 0x0080, 0x0080, 0x0080};

  for (int m4 = 0; m4 < 32; m4 += 4) {
    const int sb = m4 >> 1;                 // readlane pair base
#pragma unroll
    for (int t = 0; t < 4; ++t) {
      const int step = m4 + t;
      // prefetch step+2 (clamped; dup loads at the tail are harmless)
      const int pf = (step < 30) ? step + 2 : 31;
      const float* Pf = abc + (long)pf * 768 + lofs;
      f32x4 fa = *(const f32x4*)(Pf);
      f32x4 fb = *(const f32x4*)(Pf + 4);
      f32x4 fc = *(const f32x4*)(Pf + 8);

      // ---- phase A: pack previous D quads -> bf16 B-frags ----
      s16x4 bfr[4];
#pragma unroll
      for (int s = 0; s < 4; ++s) {
        uint2 nq;
        nq.x = pk_bf16t(Dv[s][0], Dv[s][1]);
        nq.y = pk_bf16t(Dv[s][2], Dv[s][3]);
        bfr[s] = __builtin_bit_cast(s16x4, nq);
      }

      f32x2 c01 = {cc[0], cc[1]}, c23 = {cc[2], cc[3]};
      f32x2 b01 = {cb[0], cb[1]}, b23 = {cb[2], cb[3]};
      f32x2 a01 = {ca[0], ca[1]}, a23 = {ca[2], ca[3]};

      // ---- phase B: A-frags + MFMAs ----
#pragma unroll
      for (int s = 0; s < 4; ++s) {
        float xs = rdlane(xq[t & 1], s * 16 + sb + (t >> 1));
        f32x2 xx = {xs, xs};
        f32x2 u01 = __builtin_elementwise_fma(
                        __builtin_elementwise_fma(c01, xx, b01), xx, a01);
        f32x2 u23 = __builtin_elementwise_fma(
                        __builtin_elementwise_fma(c23, xx, b23), xx, a23);
        uint2 at;
        at.x = pk_lo16(u01);
        at.y = pk_lo16(u23);
        s16x4 af = __builtin_elementwise_max(__builtin_bit_cast(s16x4, at), clmp);
        Dv[s] = __builtin_amdgcn_mfma_f32_16x16x16bf16_1k(af, bfr[s], zero,
                                                          0, 0, 0);
      }
      // rotate param pipeline
      ca = na_; cb = nb_; cc = nc_;
      na_ = fa; nb_ = fb; nc_ = fc;
    }
  }

  // y_s = sum_r v[r]: f32 state -> sum 4 regs, reduce across quads
  float res = 0.0f;
#pragma unroll
  for (int s = 0; s < 4; ++s) {
    float t = (Dv[s][0] + Dv[s][1]) + (Dv[s][2] + Dv[s][3]);
    t += __shfl_xor(t, 16, 64);
    t += __shfl_xor(t, 32, 64);
    if (l == s) res = t;
  }
  if (l < 4) {
    long n0 = nb + l;
    if (n0 < (long)N) out[n0] = logf(res + EPSV);
  }
}

// ---------------------------------------------------------------------------
// Generic fallback (any M) — same math, per-sample scalar x loads.
// ---------------------------------------------------------------------------
__global__ __launch_bounds__(256, 4)
void tt_main_gen(const float* __restrict__ X,
                 const float* __restrict__ wk0_logits,
                 const float* __restrict__ abc,
                 float* __restrict__ out, int N, int M) {
  const int l = (int)(threadIdx.x & 63u);
  const int wave = __builtin_amdgcn_readfirstlane((int)(threadIdx.x >> 6));
  const int c = l & 15;
  const int q = l >> 4;

  long nb = ((long)blockIdx.x * 4 + wave) * 8;
  if (nb > (long)N - 8) nb = (long)N - 8;

  float wl = wk0_logits[c];
  float mx = wl;
#pragma unroll
  for (int d = 1; d < 16; d <<= 1) mx = fmaxf(mx, __shfl_xor(mx, d, 64));
  float ew = fexp2((wl - mx) * LOG2E);
  float sw = ew;
#pragma unroll
  for (int d = 1; d < 16; d <<= 1) sw += __shfl_xor(sw, d, 64);
  float w0 = ew / sw;

  f32x4 q0;
#pragma unroll
  for (int i = 0; i < 4; ++i) q0[i] = __shfl(w0, 4 * q + i, 64);
  f32x4 Dv[8];
#pragma unroll
  for (int s = 0; s < 8; ++s) Dv[s] = q0;

  const float* Xn = X + nb * (long)M;
  const f32x4* Pm = (const f32x4*)abc + (c * 4 + q) * 3;
  f32x4 pa = Pm[0], pb = Pm[1], pc = Pm[2];
  const f32x4 zero = (f32x4){0.f, 0.f, 0.f, 0.f};
  const s16x4 clmp = (s16x4){0x0080, 0x0080, 0x0080, 0x0080};

  for (int m = 0; m < M; ++m) {
    f32x4 qa, qb4, qc;
    const f32x4* Pn = Pm + 192;
    bool more = (m + 1 < M);
    if (more) { qa = Pn[0]; qb4 = Pn[1]; qc = Pn[2]; }
    s16x4 bfr[8];
#pragma unroll
    for (int s = 0; s < 8; ++s) {
      uint2 nq;
      nq.x = pk_bf16t(Dv[s][0], Dv[s][1]);
      nq.y = pk_bf16t(Dv[s][2], Dv[s][3]);
      bfr[s] = __builtin_bit_cast(s16x4, nq);
    }
#pragma unroll
    for (int s = 0; s < 8; ++s) {
      float xs = Xn[(long)s * M + m];
      f32x2 xx = {xs, xs};
      f32x2 c01 = {pc[0], pc[1]}, c23 = {pc[2], pc[3]};
      f32x2 b01 = {pb[0], pb[1]}, b23 = {pb[2], pb[3]};
      f32x2 a01 = {pa[0], pa[1]}, a23 = {pa[2], pa[3]};
      f32x2 u01 = __builtin_elementwise_fma(
                      __builtin_elementwise_fma(c01, xx, b01), xx, a01);
      f32x2 u23 = __builtin_elementwise_fma(
                      __builtin_elementwise_fma(c23, xx, b23), xx, a23);
      uint2 at;
      at.x = pk_lo16(u01);
      at.y = pk_lo16(u23);
      s16x4 af = __builtin_elementwise_max(__builtin_bit_cast(s16x4, at), clmp);
      Dv[s] = __builtin_amdgcn_mfma_f32_16x16x16bf16_1k(af, bfr[s], zero,
                                                        0, 0, 0);
    }
    if (more) { pa = qa; pb = qb4; pc = qc; Pm = Pn; }
  }

  float res = 0.0f;
#pragma unroll
  for (int s = 0; s < 8; ++s) {
    float t = (Dv[s][0] + Dv[s][1]) + (Dv[s][2] + Dv[s][3]);
    t += __shfl_xor(t, 16, 64);
    t += __shfl_xor(t, 32, 64);
    if (l == s) res = t;
  }
  if (l < 8) {
    long n0 = nb + l;
    if (n0 < (long)N) out[n0] = logf(res + EPSV);
  }
}

extern "C" void kernel_launch(void* const* d_in, const int* in_sizes, int n_in,
                              void* d_out, int out_size, void* d_ws, size_t ws_size,
                              hipStream_t stream) {
  const float* X   = (const float*)d_in[0];
  const float* wk0 = (const float*)d_in[1];
  const float* Wl  = (const float*)d_in[2];
  const float* mu  = (const float*)d_in[3];
  const float* ps  = (const float*)d_in[4];
  int K = in_sizes[1];                 // 16
  int M = in_sizes[2] / (K * K);       // 32
  int N = in_sizes[0] / M;             // 262144
  float* abc = (float*)d_ws;           // M*64*3 float4 = 96 KB

  tt_prep<<<(M * 64 + 255) / 256, 256, 0, stream>>>(Wl, mu, ps, abc, M);
  if (M == 32) {
    int blocks = (int)((N + 15) / 16);   // 4 samples/wave, 4 waves/block
    tt_main32<<<blocks, 256, 0, stream>>>(X, wk0, abc, (float*)d_out, N);
  } else {
    int blocks = (int)((N + 31) / 32);
    tt_main_gen<<<blocks, 256, 0, stream>>>(X, wk0, abc, (float*)d_out, N, M);
  }
}

// Round 5
// 312.951 us; speedup vs baseline: 1.3629x; 1.3629x over previous
//
#include <hip/hip_runtime.h>
#include <math.h>

typedef __attribute__((ext_vector_type(4))) float f32x4;
typedef __attribute__((ext_vector_type(2))) float f32x2;
typedef __attribute__((ext_vector_type(4))) short s16x4;

#define LOG2E   1.4426950408889634f
#define EPSV    2.220446049250313e-16f
#define HLOG2PI 0.9189385332046727f

// Schraudolph-to-bf16: U = e128 + MAGIC (f32 add rounds to ulp=1 since
// U in [2^23,2^24)); low16(bits(U)) == bf16 bits of ~2^(e128/128).
// MAGIC = 1.5*2^23 + 127*128 + (128*sigma - 0.5), sigma = -0.0573.
// MAGIC is folded into the 'a' coefficient at prep time.
#define MAGICC  12599160.0f

static __device__ __forceinline__ float fexp2(float x) {
  return __builtin_amdgcn_exp2f(x);
}

// [hi16(f1)]:[hi16(f0)] -> bf16 trunc pack, one v_perm_b32
static __device__ __forceinline__ unsigned pk_bf16t(float f0, float f1) {
  return __builtin_amdgcn_perm(__builtin_bit_cast(unsigned, f1),
                               __builtin_bit_cast(unsigned, f0), 0x07060302u);
}
// [lo16(u1)]:[lo16(u0)] -> Schraudolph bf16 bits, one v_perm_b32
static __device__ __forceinline__ unsigned pk_lo16(f32x2 u) {
  return __builtin_amdgcn_perm(__builtin_bit_cast(uint2, u).y,
                               __builtin_bit_cast(uint2, u).x, 0x05040100u);
}

// Quadratic u = a + x*(b + x*c) on 4 entries as exactly 4 v_pk_fma_f32.
// x broadcast comes in as an SGPR PAIR (both halves = x, built by SALU --
// free pipe), so no per-sample v_mov splats. Non-volatile: scheduler free.
static __device__ __forceinline__ void quad4(f32x2& u01, f32x2& u23,
    f32x2 c01, f32x2 c23, f32x2 b01, f32x2 b23, f32x2 a01, f32x2 a23,
    unsigned long long xx) {
  f32x2 t01, t23;
  asm("v_pk_fma_f32 %0, %2, %8, %4\n\t"
      "v_pk_fma_f32 %1, %3, %8, %5\n\t"
      "v_pk_fma_f32 %0, %0, %8, %6\n\t"
      "v_pk_fma_f32 %1, %1, %8, %7"
      : "=&v"(t01), "=&v"(t23)
      : "v"(c01), "v"(c23), "v"(b01), "v"(b23), "v"(a01), "v"(a23),
        "s"(xx));
  u01 = t01;
  u23 = t23;
}

// MFMA via inline asm with all-"v" constraints: keeps D/A/B/C in arch
// VGPRs (the builtin homes them in AGPRs -> ~12-16 v_accvgpr_read/write
// per sample-step, the measured ~2.5x VALU inflation). s_nop 1 covers the
// VALU-write -> MFMA-read-src hazard (2 wait states); the D-result is
// consumed a full step (~100 instrs) later, so no trailing hazard.
// Non-volatile: scheduler may hoist/sink it freely.
static __device__ __forceinline__ f32x4 mfma_v(s16x4 a, s16x4 b, f32x4 c) {
  f32x4 d;
  asm("s_nop 1\n\t"
      "v_mfma_f32_16x16x16_bf16 %0, %1, %2, %3"
      : "=&v"(d)
      : "v"(a), "v"(b), "v"(c));
  return d;
}

static __device__ __forceinline__ unsigned rdlane_u(float v, int lane) {
  return (unsigned)__builtin_amdgcn_readlane(__builtin_bit_cast(int, v), lane);
}

// ---------------------------------------------------------------------------
// Prep: fold log_softmax(W_logits, axis=1), softplus(pre_sigma), mu into
// per-entry quadratic coefficients scaled by 128*log2(e), with the
// Schraudolph magic constant folded into 'a':
//   U[m,k,j](x) = a + b*x + c*x^2 ;  low16(bits(U)) = bf16(R entry)
// Layout: group g = m*64 + k*4 + q  (q = j/4) -> 3 consecutive float4 {a,b,c}.
// ---------------------------------------------------------------------------
__global__ void tt_prep(const float* __restrict__ Wl,
                        const float* __restrict__ mu,
                        const float* __restrict__ ps,
                        float* __restrict__ abc, int M) {
  int g = blockIdx.x * blockDim.x + threadIdx.x;
  if (g >= M * 64) return;
  int m = g >> 6;
  int k = (g >> 2) & 15;
  int q = g & 3;
  const float SC = 128.0f * LOG2E;
  float av[4], bv[4], cv[4];
#pragma unroll
  for (int i = 0; i < 4; ++i) {
    int j = q * 4 + i;
    int base = m * 256 + j;               // stride 16 over k'
    float mx = -INFINITY;
    for (int kk = 0; kk < 16; ++kk) mx = fmaxf(mx, Wl[base + kk * 16]);
    float s = 0.f;
    for (int kk = 0; kk < 16; ++kk) s += expf(Wl[base + kk * 16] - mx);
    float lse = mx + logf(s);
    int idx = m * 256 + k * 16 + j;
    float logw = Wl[idx] - lse;
    float p  = ps[idx];
    float sg = (p > 20.f) ? p : log1pf(expf(p));   // softplus
    float inv  = 1.0f / sg;
    float inv2 = inv * inv;
    float muv  = mu[idx];
    av[i] = SC * (logw - logf(sg) - HLOG2PI - 0.5f * muv * muv * inv2) + MAGICC;
    bv[i] = SC * (muv * inv2);
    cv[i] = SC * (-0.5f * inv2);
  }
  f32x4* o = (f32x4*)abc + (long)g * 3;
  o[0] = (f32x4){av[0], av[1], av[2], av[3]};
  o[1] = (f32x4){bv[0], bv[1], bv[2], bv[3]};
  o[2] = (f32x4){cv[0], cv[1], cv[2], cv[3]};
}

// ---------------------------------------------------------------------------
// Specialized main for M == 32. One wave = 8 samples (round-0 structure).
// Two-phase step to break the MFMA->pack RAW hazard:
//   phase A: pack ALL 8 previous-step D quads (f32) into bf16 B-frags.
//   phase B: per sample: readlane x -> SGPR-pair broadcast, quadratic via
//            4 asm v_pk_fma_f32, Schraudolph lo16 pack + i16 clamp ->
//            A-frag, asm MFMA (arch-VGPR operands).
// Params double-prefetched (2 steps ahead) to cover L2 latency.
// ---------------------------------------------------------------------------
__global__ __launch_bounds__(256, 4)
void tt_main32(const float* __restrict__ X,
               const float* __restrict__ wk0_logits,
               const float* __restrict__ abc,
               float* __restrict__ out, int N) {
  const int l = (int)(threadIdx.x & 63u);
  const int wave = __builtin_amdgcn_readfirstlane((int)(threadIdx.x >> 6));
  const int c = l & 15;   // A row / D col
  const int q = l >> 4;   // quad

  long nb = ((long)blockIdx.x * 4 + wave) * 8;
  if (nb > (long)N - 8) nb = (long)N - 8;   // tail clamp (duplicate work ok)

  // wk0 = softmax(wk0_logits); seed f32 state with wk0 (C/D-frag layout)
  float wl = wk0_logits[c];
  float mx = wl;
#pragma unroll
  for (int d = 1; d < 16; d <<= 1) mx = fmaxf(mx, __shfl_xor(mx, d, 64));
  float ew = fexp2((wl - mx) * LOG2E);
  float sw = ew;
#pragma unroll
  for (int d = 1; d < 16; d <<= 1) sw += __shfl_xor(sw, d, 64);
  float w0 = ew / sw;

  f32x4 q0;
#pragma unroll
  for (int i = 0; i < 4; ++i) q0[i] = __shfl(w0, 4 * q + i, 64);

  f32x4 Dv[8];
#pragma unroll
  for (int s = 0; s < 8; ++s) Dv[s] = q0;

  // one vector load: all 256 x values for this wave
  const float* Xn = X + nb * 32;
  f32x4 xq = *(const f32x4*)(Xn + l * 4);

  const int lofs = (c * 4 + q) * 12;        // per-lane float offset into a step
  // param pipeline: cur = step0, nxt = step1 (in flight), fut loaded per step
  f32x4 ca = *(const f32x4*)(abc + lofs);
  f32x4 cb = *(const f32x4*)(abc + lofs + 4);
  f32x4 cc = *(const f32x4*)(abc + lofs + 8);
  f32x4 na_ = *(const f32x4*)(abc + 768 + lofs);
  f32x4 nb_ = *(const f32x4*)(abc + 768 + lofs + 4);
  f32x4 nc_ = *(const f32x4*)(abc + 768 + lofs + 8);

  const f32x4 zero = (f32x4){0.f, 0.f, 0.f, 0.f};
  const s16x4 clmp = (s16x4){0x0080, 0x0080, 0x0080, 0x0080};

  for (int m4 = 0; m4 < 32; m4 += 4) {
    const int sb = m4 >> 2;                 // readlane base
#pragma unroll
    for (int t = 0; t < 4; ++t) {
      const int step = m4 + t;
      // prefetch step+2 (clamped; dup loads at the tail are harmless)
      const int pf = (step < 30) ? step + 2 : 31;
      const float* Pf = abc + (long)pf * 768 + lofs;
      f32x4 fa = *(const f32x4*)(Pf);
      f32x4 fb = *(const f32x4*)(Pf + 4);
      f32x4 fc = *(const f32x4*)(Pf + 8);

      // ---- phase A: pack previous D quads -> bf16 B-frags ----
      s16x4 bfr[8];
#pragma unroll
      for (int s = 0; s < 8; ++s) {
        uint2 nq;
        nq.x = pk_bf16t(Dv[s][0], Dv[s][1]);
        nq.y = pk_bf16t(Dv[s][2], Dv[s][3]);
        bfr[s] = __builtin_bit_cast(s16x4, nq);
      }

      f32x2 c01 = {cc[0], cc[1]}, c23 = {cc[2], cc[3]};
      f32x2 b01 = {cb[0], cb[1]}, b23 = {cb[2], cb[3]};
      f32x2 a01 = {ca[0], ca[1]}, a23 = {ca[2], ca[3]};

      // ---- phase B: A-frags + MFMAs ----
#pragma unroll
      for (int s = 0; s < 8; ++s) {
        unsigned xi = rdlane_u(xq[t], sb + s * 8);
        unsigned long long xx =
            ((unsigned long long)xi << 32) | (unsigned long long)xi;
        f32x2 u01, u23;
        quad4(u01, u23, c01, c23, b01, b23, a01, a23, xx);
        uint2 at;
        at.x = pk_lo16(u01);
        at.y = pk_lo16(u23);
        s16x4 af = __builtin_elementwise_max(__builtin_bit_cast(s16x4, at), clmp);
        Dv[s] = mfma_v(af, bfr[s], zero);
      }
      // rotate param pipeline
      ca = na_; cb = nb_; cc = nc_;
      na_ = fa; nb_ = fb; nc_ = fc;
    }
  }

  // y_s = sum_r v[r]: f32 state -> sum 4 regs, reduce across quads
  float res = 0.0f;
#pragma unroll
  for (int s = 0; s < 8; ++s) {
    float t = (Dv[s][0] + Dv[s][1]) + (Dv[s][2] + Dv[s][3]);
    t += __shfl_xor(t, 16, 64);
    t += __shfl_xor(t, 32, 64);
    if (l == s) res = t;
  }
  if (l < 8) {
    long n0 = nb + l;
    if (n0 < (long)N) out[n0] = logf(res + EPSV);
  }
}

// ---------------------------------------------------------------------------
// Generic fallback (any M) — same math, per-sample scalar x loads.
// ---------------------------------------------------------------------------
__global__ __launch_bounds__(256, 4)
void tt_main_gen(const float* __restrict__ X,
                 const float* __restrict__ wk0_logits,
                 const float* __restrict__ abc,
                 float* __restrict__ out, int N, int M) {
  const int l = (int)(threadIdx.x & 63u);
  const int wave = __builtin_amdgcn_readfirstlane((int)(threadIdx.x >> 6));
  const int c = l & 15;
  const int q = l >> 4;

  long nb = ((long)blockIdx.x * 4 + wave) * 8;
  if (nb > (long)N - 8) nb = (long)N - 8;

  float wl = wk0_logits[c];
  float mx = wl;
#pragma unroll
  for (int d = 1; d < 16; d <<= 1) mx = fmaxf(mx, __shfl_xor(mx, d, 64));
  float ew = fexp2((wl - mx) * LOG2E);
  float sw = ew;
#pragma unroll
  for (int d = 1; d < 16; d <<= 1) sw += __shfl_xor(sw, d, 64);
  float w0 = ew / sw;

  f32x4 q0;
#pragma unroll
  for (int i = 0; i < 4; ++i) q0[i] = __shfl(w0, 4 * q + i, 64);
  f32x4 Dv[8];
#pragma unroll
  for (int s = 0; s < 8; ++s) Dv[s] = q0;

  const float* Xn = X + nb * (long)M;
  const f32x4* Pm = (const f32x4*)abc + (c * 4 + q) * 3;
  f32x4 pa = Pm[0], pb = Pm[1], pc = Pm[2];
  const f32x4 zero = (f32x4){0.f, 0.f, 0.f, 0.f};
  const s16x4 clmp = (s16x4){0x0080, 0x0080, 0x0080, 0x0080};

  for (int m = 0; m < M; ++m) {
    f32x4 qa, qb4, qc;
    const f32x4* Pn = Pm + 192;
    bool more = (m + 1 < M);
    if (more) { qa = Pn[0]; qb4 = Pn[1]; qc = Pn[2]; }
    s16x4 bfr[8];
#pragma unroll
    for (int s = 0; s < 8; ++s) {
      uint2 nq;
      nq.x = pk_bf16t(Dv[s][0], Dv[s][1]);
      nq.y = pk_bf16t(Dv[s][2], Dv[s][3]);
      bfr[s] = __builtin_bit_cast(s16x4, nq);
    }
#pragma unroll
    for (int s = 0; s < 8; ++s) {
      float xs = Xn[(long)s * M + m];
      f32x2 xx = {xs, xs};
      f32x2 c01 = {pc[0], pc[1]}, c23 = {pc[2], pc[3]};
      f32x2 b01 = {pb[0], pb[1]}, b23 = {pb[2], pb[3]};
      f32x2 a01 = {pa[0], pa[1]}, a23 = {pa[2], pa[3]};
      f32x2 u01 = __builtin_elementwise_fma(
                      __builtin_elementwise_fma(c01, xx, b01), xx, a01);
      f32x2 u23 = __builtin_elementwise_fma(
                      __builtin_elementwise_fma(c23, xx, b23), xx, a23);
      uint2 at;
      at.x = pk_lo16(u01);
      at.y = pk_lo16(u23);
      s16x4 af = __builtin_elementwise_max(__builtin_bit_cast(s16x4, at), clmp);
      Dv[s] = __builtin_amdgcn_mfma_f32_16x16x16bf16_1k(af, bfr[s], zero,
                                                        0, 0, 0);
    }
    if (more) { pa = qa; pb = qb4; pc = qc; Pm = Pn; }
  }

  float res = 0.0f;
#pragma unroll
  for (int s = 0; s < 8; ++s) {
    float t = (Dv[s][0] + Dv[s][1]) + (Dv[s][2] + Dv[s][3]);
    t += __shfl_xor(t, 16, 64);
    t += __shfl_xor(t, 32, 64);
    if (l == s) res = t;
  }
  if (l < 8) {
    long n0 = nb + l;
    if (n0 < (long)N) out[n0] = logf(res + EPSV);
  }
}

extern "C" void kernel_launch(void* const* d_in, const int* in_sizes, int n_in,
                              void* d_out, int out_size, void* d_ws, size_t ws_size,
                              hipStream_t stream) {
  const float* X   = (const float*)d_in[0];
  const float* wk0 = (const float*)d_in[1];
  const float* Wl  = (const float*)d_in[2];
  const float* mu  = (const float*)d_in[3];
  const float* ps  = (const float*)d_in[4];
  int K = in_sizes[1];                 // 16
  int M = in_sizes[2] / (K * K);       // 32
  int N = in_sizes[0] / M;             // 262144
  float* abc = (float*)d_ws;           // M*64*3 float4 = 96 KB

  tt_prep<<<(M * 64 + 255) / 256, 256, 0, stream>>>(Wl, mu, ps, abc, M);
  int blocks = (int)((N + 31) / 32);
  if (M == 32) {
    tt_main32<<<blocks, 256, 0, stream>>>(X, wk0, abc, (float*)d_out, N);
  } else {
    tt_main_gen<<<blocks, 256, 0, stream>>>(X, wk0, abc, (float*)d_out, N, M);
  }
}

// Round 6
// 294.211 us; speedup vs baseline: 1.4497x; 1.0637x over previous
//
#include <hip/hip_runtime.h>
#include <math.h>

typedef __attribute__((ext_vector_type(4))) float f32x4;
typedef __attribute__((ext_vector_type(2))) float f32x2;
typedef __attribute__((ext_vector_type(4))) short s16x4;

#define LOG2E   1.4426950408889634f
#define EPSV    2.220446049250313e-16f
#define HLOG2PI 0.9189385332046727f

// Schraudolph-to-bf16: U = e128 + MAGIC (f32 add rounds to ulp=1 since
// U in [2^23,2^24)); low16(bits(U)) == bf16 bits of ~2^(e128/128).
// MAGIC = 1.5*2^23 + 127*128 + (128*sigma - 0.5), sigma = -0.0573.
// MAGIC is folded into the 'a' coefficient at prep time.
#define MAGICC  12599160.0f

static __device__ __forceinline__ float fexp2(float x) {
  return __builtin_amdgcn_exp2f(x);
}

// [hi16(f1)]:[hi16(f0)] -> bf16 trunc pack, one v_perm_b32
static __device__ __forceinline__ unsigned pk_bf16t(float f0, float f1) {
  return __builtin_amdgcn_perm(__builtin_bit_cast(unsigned, f1),
                               __builtin_bit_cast(unsigned, f0), 0x07060302u);
}
// [lo16(u1)]:[lo16(u0)] -> Schraudolph bf16 bits, one v_perm_b32
static __device__ __forceinline__ unsigned pk_lo16(f32x2 u) {
  return __builtin_amdgcn_perm(__builtin_bit_cast(uint2, u).y,
                               __builtin_bit_cast(uint2, u).x, 0x05040100u);
}

// Quadratic u = a + x*(b + x*c) on 4 entries as exactly 4 v_pk_fma_f32.
// x broadcast comes in as an SGPR PAIR (both halves = x). readlane's dest
// is already an SGPR; the pair build is SALU (free pipe) -> this deletes
// the 2 per-sample v_mov splats the builtin path emits. Non-volatile:
// scheduler is free to interleave across samples/steps.
static __device__ __forceinline__ void quad4(f32x2& u01, f32x2& u23,
    f32x2 c01, f32x2 c23, f32x2 b01, f32x2 b23, f32x2 a01, f32x2 a23,
    unsigned long long xx) {
  f32x2 t01, t23;
  asm("v_pk_fma_f32 %0, %2, %8, %4\n\t"
      "v_pk_fma_f32 %1, %3, %8, %5\n\t"
      "v_pk_fma_f32 %0, %0, %8, %6\n\t"
      "v_pk_fma_f32 %1, %1, %8, %7"
      : "=&v"(t01), "=&v"(t23)
      : "v"(c01), "v"(c23), "v"(b01), "v"(b23), "v"(a01), "v"(a23),
        "s"(xx));
  u01 = t01;
  u23 = t23;
}

static __device__ __forceinline__ unsigned rdlane_u(float v, int lane) {
  return (unsigned)__builtin_amdgcn_readlane(__builtin_bit_cast(int, v), lane);
}

// ---------------------------------------------------------------------------
// Prep: fold log_softmax(W_logits, axis=1), softplus(pre_sigma), mu into
// per-entry quadratic coefficients scaled by 128*log2(e), with the
// Schraudolph magic constant folded into 'a':
//   U[m,k,j](x) = a + b*x + c*x^2 ;  low16(bits(U)) = bf16(R entry)
// Layout: group g = m*64 + k*4 + q  (q = j/4) -> 3 consecutive float4 {a,b,c}.
// ---------------------------------------------------------------------------
__global__ void tt_prep(const float* __restrict__ Wl,
                        const float* __restrict__ mu,
                        const float* __restrict__ ps,
                        float* __restrict__ abc, int M) {
  int g = blockIdx.x * blockDim.x + threadIdx.x;
  if (g >= M * 64) return;
  int m = g >> 6;
  int k = (g >> 2) & 15;
  int q = g & 3;
  const float SC = 128.0f * LOG2E;
  float av[4], bv[4], cv[4];
#pragma unroll
  for (int i = 0; i < 4; ++i) {
    int j = q * 4 + i;
    int base = m * 256 + j;               // stride 16 over k'
    float mx = -INFINITY;
    for (int kk = 0; kk < 16; ++kk) mx = fmaxf(mx, Wl[base + kk * 16]);
    float s = 0.f;
    for (int kk = 0; kk < 16; ++kk) s += expf(Wl[base + kk * 16] - mx);
    float lse = mx + logf(s);
    int idx = m * 256 + k * 16 + j;
    float logw = Wl[idx] - lse;
    float p  = ps[idx];
    float sg = (p > 20.f) ? p : log1pf(expf(p));   // softplus
    float inv  = 1.0f / sg;
    float inv2 = inv * inv;
    float muv  = mu[idx];
    av[i] = SC * (logw - logf(sg) - HLOG2PI - 0.5f * muv * muv * inv2) + MAGICC;
    bv[i] = SC * (muv * inv2);
    cv[i] = SC * (-0.5f * inv2);
  }
  f32x4* o = (f32x4*)abc + (long)g * 3;
  o[0] = (f32x4){av[0], av[1], av[2], av[3]};
  o[1] = (f32x4){bv[0], bv[1], bv[2], bv[3]};
  o[2] = (f32x4){cv[0], cv[1], cv[2], cv[3]};
}

// ---------------------------------------------------------------------------
// Specialized main for M == 32. One wave = 8 samples (r0 structure).
// Two-phase step to break the MFMA->pack RAW hazard:
//   phase A: pack ALL 8 previous-step D quads (f32) into bf16 B-frags.
//   phase B: per sample: readlane x -> SGPR pair, quadratic via 4 asm
//            v_pk_fma_f32, Schraudolph lo16 pack + i16 clamp -> A-frag,
//            builtin MFMA (compiler-managed hazards, no nops).
// FULL 32-step unroll: the 4-step body + backedge forced ~9 f32x4
// rotation movs/step + a pf select + address increments; full unroll
// makes the param pipeline pure SSA (zero movs), pf and all load offsets
// compile-time, and lets the scheduler interleave across steps.
// Params double-prefetched (2 steps ahead) to cover L2 latency.
// ---------------------------------------------------------------------------
__global__ __launch_bounds__(256, 4)
void tt_main32(const float* __restrict__ X,
               const float* __restrict__ wk0_logits,
               const float* __restrict__ abc,
               float* __restrict__ out, int N) {
  const int l = (int)(threadIdx.x & 63u);
  const int wave = __builtin_amdgcn_readfirstlane((int)(threadIdx.x >> 6));
  const int c = l & 15;   // A row / D col
  const int q = l >> 4;   // quad

  long nb = ((long)blockIdx.x * 4 + wave) * 8;
  if (nb > (long)N - 8) nb = (long)N - 8;   // tail clamp (duplicate work ok)

  // wk0 = softmax(wk0_logits); seed f32 state with wk0 (C/D-frag layout)
  float wl = wk0_logits[c];
  float mx = wl;
#pragma unroll
  for (int d = 1; d < 16; d <<= 1) mx = fmaxf(mx, __shfl_xor(mx, d, 64));
  float ew = fexp2((wl - mx) * LOG2E);
  float sw = ew;
#pragma unroll
  for (int d = 1; d < 16; d <<= 1) sw += __shfl_xor(sw, d, 64);
  float w0 = ew / sw;

  f32x4 q0;
#pragma unroll
  for (int i = 0; i < 4; ++i) q0[i] = __shfl(w0, 4 * q + i, 64);

  f32x4 Dv[8];
#pragma unroll
  for (int s = 0; s < 8; ++s) Dv[s] = q0;

  // one vector load: all 256 x values for this wave
  const float* Xn = X + nb * 32;
  f32x4 xq = *(const f32x4*)(Xn + l * 4);

  const int lofs = (c * 4 + q) * 12;        // per-lane float offset into a step
  // param pipeline: cur = step0, nxt = step1 (in flight), fut loaded per step
  f32x4 ca = *(const f32x4*)(abc + lofs);
  f32x4 cb = *(const f32x4*)(abc + lofs + 4);
  f32x4 cc = *(const f32x4*)(abc + lofs + 8);
  f32x4 na_ = *(const f32x4*)(abc + 768 + lofs);
  f32x4 nb_ = *(const f32x4*)(abc + 768 + lofs + 4);
  f32x4 nc_ = *(const f32x4*)(abc + 768 + lofs + 8);

  const f32x4 zero = (f32x4){0.f, 0.f, 0.f, 0.f};
  const s16x4 clmp = (s16x4){0x0080, 0x0080, 0x0080, 0x0080};

#pragma unroll
  for (int step = 0; step < 32; ++step) {
    // prefetch step+2 (clamped; dup loads at the tail are harmless);
    // compile-time constant offsets after unroll
    const int pf = (step < 30) ? step + 2 : 31;
    const float* Pf = abc + (long)pf * 768 + lofs;
    f32x4 fa = *(const f32x4*)(Pf);
    f32x4 fb = *(const f32x4*)(Pf + 4);
    f32x4 fc = *(const f32x4*)(Pf + 8);

    // ---- phase A: pack previous D quads -> bf16 B-frags ----
    s16x4 bfr[8];
#pragma unroll
    for (int s = 0; s < 8; ++s) {
      uint2 nq;
      nq.x = pk_bf16t(Dv[s][0], Dv[s][1]);
      nq.y = pk_bf16t(Dv[s][2], Dv[s][3]);
      bfr[s] = __builtin_bit_cast(s16x4, nq);
    }

    f32x2 c01 = {cc[0], cc[1]}, c23 = {cc[2], cc[3]};
    f32x2 b01 = {cb[0], cb[1]}, b23 = {cb[2], cb[3]};
    f32x2 a01 = {ca[0], ca[1]}, a23 = {ca[2], ca[3]};

    // ---- phase B: A-frags + MFMAs ----
#pragma unroll
    for (int s = 0; s < 8; ++s) {
      unsigned xi = rdlane_u(xq[step & 3], (step >> 2) + s * 8);
      unsigned long long xx =
          ((unsigned long long)xi << 32) | (unsigned long long)xi;
      f32x2 u01, u23;
      quad4(u01, u23, c01, c23, b01, b23, a01, a23, xx);
      uint2 at;
      at.x = pk_lo16(u01);
      at.y = pk_lo16(u23);
      s16x4 af = __builtin_elementwise_max(__builtin_bit_cast(s16x4, at), clmp);
      Dv[s] = __builtin_amdgcn_mfma_f32_16x16x16bf16_1k(af, bfr[s], zero,
                                                        0, 0, 0);
    }
    // rotate param pipeline (pure SSA renaming under full unroll)
    ca = na_; cb = nb_; cc = nc_;
    na_ = fa; nb_ = fb; nc_ = fc;
  }

  // y_s = sum_r v[r]: f32 state -> sum 4 regs, reduce across quads
  float res = 0.0f;
#pragma unroll
  for (int s = 0; s < 8; ++s) {
    float t = (Dv[s][0] + Dv[s][1]) + (Dv[s][2] + Dv[s][3]);
    t += __shfl_xor(t, 16, 64);
    t += __shfl_xor(t, 32, 64);
    if (l == s) res = t;
  }
  if (l < 8) {
    long n0 = nb + l;
    if (n0 < (long)N) out[n0] = logf(res + EPSV);
  }
}

// ---------------------------------------------------------------------------
// Generic fallback (any M) — same math, per-sample scalar x loads.
// ---------------------------------------------------------------------------
__global__ __launch_bounds__(256, 4)
void tt_main_gen(const float* __restrict__ X,
                 const float* __restrict__ wk0_logits,
                 const float* __restrict__ abc,
                 float* __restrict__ out, int N, int M) {
  const int l = (int)(threadIdx.x & 63u);
  const int wave = __builtin_amdgcn_readfirstlane((int)(threadIdx.x >> 6));
  const int c = l & 15;
  const int q = l >> 4;

  long nb = ((long)blockIdx.x * 4 + wave) * 8;
  if (nb > (long)N - 8) nb = (long)N - 8;

  float wl = wk0_logits[c];
  float mx = wl;
#pragma unroll
  for (int d = 1; d < 16; d <<= 1) mx = fmaxf(mx, __shfl_xor(mx, d, 64));
  float ew = fexp2((wl - mx) * LOG2E);
  float sw = ew;
#pragma unroll
  for (int d = 1; d < 16; d <<= 1) sw += __shfl_xor(sw, d, 64);
  float w0 = ew / sw;

  f32x4 q0;
#pragma unroll
  for (int i = 0; i < 4; ++i) q0[i] = __shfl(w0, 4 * q + i, 64);
  f32x4 Dv[8];
#pragma unroll
  for (int s = 0; s < 8; ++s) Dv[s] = q0;

  const float* Xn = X + nb * (long)M;
  const f32x4* Pm = (const f32x4*)abc + (c * 4 + q) * 3;
  f32x4 pa = Pm[0], pb = Pm[1], pc = Pm[2];
  const f32x4 zero = (f32x4){0.f, 0.f, 0.f, 0.f};
  const s16x4 clmp = (s16x4){0x0080, 0x0080, 0x0080, 0x0080};

  for (int m = 0; m < M; ++m) {
    f32x4 qa, qb4, qc;
    const f32x4* Pn = Pm + 192;
    bool more = (m + 1 < M);
    if (more) { qa = Pn[0]; qb4 = Pn[1]; qc = Pn[2]; }
    s16x4 bfr[8];
#pragma unroll
    for (int s = 0; s < 8; ++s) {
      uint2 nq;
      nq.x = pk_bf16t(Dv[s][0], Dv[s][1]);
      nq.y = pk_bf16t(Dv[s][2], Dv[s][3]);
      bfr[s] = __builtin_bit_cast(s16x4, nq);
    }
#pragma unroll
    for (int s = 0; s < 8; ++s) {
      float xs = Xn[(long)s * M + m];
      f32x2 xx = {xs, xs};
      f32x2 c01 = {pc[0], pc[1]}, c23 = {pc[2], pc[3]};
      f32x2 b01 = {pb[0], pb[1]}, b23 = {pb[2], pb[3]};
      f32x2 a01 = {pa[0], pa[1]}, a23 = {pa[2], pa[3]};
      f32x2 u01 = __builtin_elementwise_fma(
                      __builtin_elementwise_fma(c01, xx, b01), xx, a01);
      f32x2 u23 = __builtin_elementwise_fma(
                      __builtin_elementwise_fma(c23, xx, b23), xx, a23);
      uint2 at;
      at.x = pk_lo16(u01);
      at.y = pk_lo16(u23);
      s16x4 af = __builtin_elementwise_max(__builtin_bit_cast(s16x4, at), clmp);
      Dv[s] = __builtin_amdgcn_mfma_f32_16x16x16bf16_1k(af, bfr[s], zero,
                                                        0, 0, 0);
    }
    if (more) { pa = qa; pb = qb4; pc = qc; Pm = Pn; }
  }

  float res = 0.0f;
#pragma unroll
  for (int s = 0; s < 8; ++s) {
    float t = (Dv[s][0] + Dv[s][1]) + (Dv[s][2] + Dv[s][3]);
    t += __shfl_xor(t, 16, 64);
    t += __shfl_xor(t, 32, 64);
    if (l == s) res = t;
  }
  if (l < 8) {
    long n0 = nb + l;
    if (n0 < (long)N) out[n0] = logf(res + EPSV);
  }
}

extern "C" void kernel_launch(void* const* d_in, const int* in_sizes, int n_in,
                              void* d_out, int out_size, void* d_ws, size_t ws_size,
                              hipStream_t stream) {
  const float* X   = (const float*)d_in[0];
  const float* wk0 = (const float*)d_in[1];
  const float* Wl  = (const float*)d_in[2];
  const float* mu  = (const float*)d_in[3];
  const float* ps  = (const float*)d_in[4];
  int K = in_sizes[1];                 // 16
  int M = in_sizes[2] / (K * K);       // 32
  int N = in_sizes[0] / M;             // 262144
  float* abc = (float*)d_ws;           // M*64*3 float4 = 96 KB

  tt_prep<<<(M * 64 + 255) / 256, 256, 0, stream>>>(Wl, mu, ps, abc, M);
  int blocks = (int)((N + 31) / 32);
  if (M == 32) {
    tt_main32<<<blocks, 256, 0, stream>>>(X, wk0, abc, (float*)d_out, N);
  } else {
    tt_main_gen<<<blocks, 256, 0, stream>>>(X, wk0, abc, (float*)d_out, N, M);
  }
}